// Round 19
// baseline (14.269 us; speedup 1.0000x reference)
//
#include <hip/hip_runtime.h>

// MosaicSDF: N=1024 points, G=512 grids, K=7 (343 nodes/grid).
// R19 = R18 + vectorized row loads. R18's residual is TA address
// throughput: 23.5M node values loaded as 23.5M scalar addresses =
// ~9.6us invariant (fits R12/R13/R17/R18). Fix: load each 7-float row
// (28B, 4B-aligned) as TWO 16B loads at A and A+12 via __builtin_memcpy
// (gfx950 supports unaligned global wide loads) -> elems 0-3 + 3-6,
// named components (static extraction), never reads outside the row ->
// no OOB anywhere (last row ends exactly at buffer end). 22 scalar ->
// ~7 wide loads per lane-chunk. Node order and math bit-identical to
// R18. Worst case (memcpy scalarizes): R18 parity.
//   Phase 1: wave w sweeps 128 grids for point w>>2 (2 ballot rounds);
//     ballot-scan compacts (rx,ry,rz,gwr)+gid per wave segment.
//   Phase 2: 32 16-lane groups drain pooled actives (CT=C0+C1); lane
//     owns (i,j)-rows {sub,sub+16,sub+32} (7 nodes each, two float4
//     loads each) + row-48 tail; static dz2 table; 4-step group reduce.
//   No atomics, no workspace, one dispatch, 18.4KB LDS -> 4 blocks/CU.

#define NPTS   1024
#define NGRIDS 512
#define TPB    512
#define NBLK   512             // 2 points per block
#define STEP   (1.0f / 6.0f)
#define FSQRT(x) __builtin_amdgcn_sqrtf(x)

__global__ __launch_bounds__(TPB, 4) void msdf_fused(
    const float* __restrict__ points,    // (N,3)
    const float* __restrict__ centers,   // (G,3)
    const float* __restrict__ scales,    // (G,)
    const float* __restrict__ vals,      // (G,343)
    float* __restrict__ out)             // (N,)
{
    __shared__ float4 s_pair[8][128];         // 16,384 B (rx,ry,rz,gwr)
    __shared__ unsigned short s_gid[8][128];  // 2,048 B
    __shared__ int   s_c[8];
    __shared__ float s_d[8];
    __shared__ float s_red[8][2];

    const int bid  = blockIdx.x;
    const int t    = threadIdx.x;
    const int w    = t >> 6;             // wave 0..7
    const int lane = t & 63;
    const int grp  = t >> 4;             // 0..31: 16-lane group (pair slot)
    const int sub  = t & 15;

    const int   n  = (bid << 1) + (w >> 2);  // this wave's point
    const float px = points[n * 3 + 0];      // wave-uniform -> scalar loads
    const float py = points[n * 3 + 1];
    const float pz = points[n * 3 + 2];

    // ---- Phase 1: activity sweep + ballot-scan compaction ----
    float dsum  = 0.0f;
    int   cbase = 0;
    #pragma unroll
    for (int r = 0; r < 2; ++r) {
        const int g = ((w & 3) << 7) + (r << 6) + lane;  // wave's 128 grids
        const float invs = 1.0f / scales[g];
        const float rx = (px - centers[g * 3 + 0]) * invs;
        const float ry = (py - centers[g * 3 + 1]) * invs;
        const float rz = (pz - centers[g * 3 + 2]) * invs;
        const float gwr = 1.0f - FSQRT(rx * rx + ry * ry + rz * rz);
        const bool  act = (gwr > 0.0f);
        const unsigned long long m = __ballot(act);
        if (act) {
            const int pos = cbase + (int)__popcll(m & ((1ull << lane) - 1ull));
            s_pair[w][pos] = make_float4(rx, ry, rz, gwr);
            s_gid[w][pos]  = (unsigned short)g;
            dsum += gwr;
        }
        cbase += (int)__popcll(m);
    }
    #pragma unroll
    for (int o = 32; o >= 1; o >>= 1) dsum += __shfl_xor(dsum, o);
    if (lane == 0) { s_c[w] = cbase; s_d[w] = dsum; }
    __syncthreads();

    const int o1 = s_c[0];
    const int o2 = o1 + s_c[1];
    const int o3 = o2 + s_c[2];
    const int o4 = o3 + s_c[3];
    const int o5 = o4 + s_c[4];
    const int o6 = o5 + s_c[5];
    const int o7 = o6 + s_c[6];
    const int CT = o7 + s_c[7];
    const float den0 = s_d[0] + s_d[1] + s_d[2] + s_d[3];
    const float den1 = s_d[4] + s_d[5] + s_d[6] + s_d[7];

    // ---- Phase 2: 32 16-lane groups, wide direct-from-L2 row loads ----
    float acc0 = 0.0f, acc1 = 0.0f;
    for (int a = grp; a < CT; a += 32) {
        const int seg = (a >= o1) + (a >= o2) + (a >= o3) + (a >= o4)
                      + (a >= o5) + (a >= o6) + (a >= o7);
        const int b0  = (seg == 0) ? 0 : (seg == 1) ? o1
                      : (seg == 2) ? o2 : (seg == 3) ? o3
                      : (seg == 4) ? o4 : (seg == 5) ? o5
                      : (seg == 6) ? o6 : o7;
        const float4 pr  = s_pair[seg][a - b0];
        const int    gid = (int)s_gid[seg][a - b0];
        const float* __restrict__ grow = vals + gid * 343;

        float dz2[7];                                // static-indexed -> regs
        #pragma unroll
        for (int l = 0; l < 7; ++l) { const float d = pr.z - l * STEP; dz2[l] = d * d; }

        float ws = 0.0f, vs = 0.0f;
        #pragma unroll
        for (int rr = 0; rr < 3; ++rr) {
            const int rowid = sub + (rr << 4);       // 0..47
            const int i = (rowid * 9363) >> 16;      // rowid / 7
            const int j = rowid - i * 7;
            const float dxv = pr.x - (float)i * STEP;
            const float dyv = pr.y - (float)j * STEP;
            const float dxy = dxv * dxv + dyv * dyv;

            // Row = 7 floats at 4B-aligned grow + rowid*7. Two 16B loads
            // at A and A+12 (overlap elem 3) stay inside the row.
            const char* __restrict__ p = (const char*)(grow + rowid * 7);
            float4 va, vb;
            __builtin_memcpy(&va, p, 16);            // elems 0..3
            __builtin_memcpy(&vb, p + 12, 16);       // elems 3..6
            const float e0 = va.x, e1 = va.y, e2 = va.z, e3 = va.w;
            const float e4 = vb.y, e5 = vb.z, e6 = vb.w;

            #define NODE(l_, v_) {                                        \
                const float d2 = dxy + dz2[l_];                           \
                const float wt = (d2 <= 1.0f) ? FSQRT(d2) : 0.0f;         \
                ws += wt;                                                 \
                vs  = fmaf(wt, v_, vs); }
            NODE(0, e0) NODE(1, e1) NODE(2, e2) NODE(3, e3)
            NODE(4, e4) NODE(5, e5) NODE(6, e6)
            #undef NODE
        }
        if (sub < 7) {                               // row 48: node (6,6,sub)
            const float dxv = pr.x - 1.0f;
            const float dyv = pr.y - 1.0f;
            const float dzv = pr.z - (float)sub * STEP;
            const float d2  = dxv * dxv + dyv * dyv + dzv * dzv;
            const float wt  = (d2 <= 1.0f) ? FSQRT(d2) : 0.0f;
            ws += wt;
            vs  = fmaf(wt, grow[336 + sub], vs);
        }
        #pragma unroll
        for (int o = 8; o >= 1; o >>= 1) {
            ws += __shfl_xor(ws, o);
            vs += __shfl_xor(vs, o);
        }
        const float interp = (ws > 0.0f) ? (vs / ws) : 0.0f;
        if (sub == 0) {
            const float contrib = interp * pr.w;
            if (seg < 4) acc0 += contrib;
            else         acc1 += contrib;
        }
    }

    // Block reduction: butterfly per wave, then cross-wave via LDS.
    #pragma unroll
    for (int o = 32; o >= 1; o >>= 1) {
        acc0 += __shfl_xor(acc0, o);
        acc1 += __shfl_xor(acc1, o);
    }
    if (lane == 0) { s_red[w][0] = acc0; s_red[w][1] = acc1; }
    __syncthreads();
    if (t < 2) {
        float nm = 0.0f;
        #pragma unroll
        for (int i = 0; i < 8; ++i) nm += s_red[i][t];
        const float dn = (t == 0) ? den0 : den1;
        out[(bid << 1) + t] = (dn > 0.0f) ? (nm / dn) : 0.0f;
    }
}

extern "C" void kernel_launch(void* const* d_in, const int* in_sizes, int n_in,
                              void* d_out, int out_size, void* d_ws, size_t ws_size,
                              hipStream_t stream) {
    const float* points  = (const float*)d_in[0];   // (1024,3)
    const float* centers = (const float*)d_in[1];   // (512,3)
    const float* scales  = (const float*)d_in[2];   // (512,)
    const float* vals    = (const float*)d_in[3];   // (512,7,7,7)
    float* out = (float*)d_out;                     // (1024,)

    msdf_fused<<<NBLK, TPB, 0, stream>>>(points, centers, scales, vals, out);
}